// Round 11
// baseline (254.617 us; speedup 1.0000x reference)
//
#include <hip/hip_runtime.h>
#include <hip/hip_bf16.h>
#include <cstdint>

typedef __bf16 bf16_t;
typedef __bf16 bf16x8 __attribute__((ext_vector_type(8)));
typedef float  f32x4  __attribute__((ext_vector_type(4)));
typedef int    i32x4  __attribute__((ext_vector_type(4)));

#define MFMA16(a, b, c) __builtin_amdgcn_mfma_f32_16x16x32_bf16((a), (b), (c), 0, 0, 0)

constexpr int BB = 8, CC = 384, NHH = 6, TT = 1024;

union U8 { uint4 u; bf16_t h[8]; };
union U2 { unsigned int u; bf16_t h[2]; };
union I4B { i32x4 i; bf16x8 v; };

static __device__ __forceinline__ void gload_lds16(const void* g, void* l) {
    __builtin_amdgcn_global_load_lds((const __attribute__((address_space(1))) void*)g,
                                     (__attribute__((address_space(3))) void*)l, 16, 0, 0);
}

// ---------------------------------------------------------------------------
// K0: one-shot weight cast fp32 -> bf16 (Wq, Wk, Wv, projW).
// ---------------------------------------------------------------------------
__global__ __launch_bounds__(256) void castw_kernel(
    const float* __restrict__ w0, const float* __restrict__ w1,
    const float* __restrict__ w2, const float* __restrict__ w3,
    bf16_t* __restrict__ d0, bf16_t* __restrict__ d1,
    bf16_t* __restrict__ d2, bf16_t* __restrict__ d3)
{
    const int wi = blockIdx.y;
    const float* s = (wi == 0) ? w0 : (wi == 1) ? w1 : (wi == 2) ? w2 : w3;
    bf16_t*      d = (wi == 0) ? d0 : (wi == 1) ? d1 : (wi == 2) ? d2 : d3;
    const int idx = (blockIdx.x * 256 + threadIdx.x) * 8;
    f32x4 a = *(const f32x4*)(s + idx);
    f32x4 b = *(const f32x4*)(s + idx + 4);
    U8 o;
    #pragma unroll
    for (int j = 0; j < 4; ++j) { o.h[j] = (bf16_t)a[j]; o.h[4 + j] = (bf16_t)b[j]; }
    *(uint4*)(d + idx) = o.u;
}

// ---------------------------------------------------------------------------
// K1: QKV projection — ROUND-9 SHAPE (t-tile 64, best measured), bf16 weights,
// fp32 x cast during staging. v-branch writes vrp[tt][b][o] partials
// (memset-free). Grid dim3(16,6,8): 6 og-blocks of one (b,tt) share an XCD.
// ---------------------------------------------------------------------------
__global__ __launch_bounds__(256) void qkv_kernel(
    const float* __restrict__ x,
    const bf16_t* __restrict__ Wq,
    const bf16_t* __restrict__ Wk,
    const bf16_t* __restrict__ Wv,
    bf16_t* __restrict__ qT,
    bf16_t* __restrict__ kT,
    bf16_t* __restrict__ vm,
    float*  __restrict__ vrp)    // [16][8][384]
{
    const int tt = blockIdx.x;
    const int og = blockIdx.y;        // 0,1:q  2,3:k  4,5:v  (og&1 = o-half)
    const int b  = blockIdx.z;
    const int t0 = tt * 64;
    const int tid  = threadIdx.x;
    const int lane = tid & 63;
    const int wid  = tid >> 6;
    const int quad = lane >> 4;
    const int l16  = lane & 15;

    __shared__ __align__(16) bf16_t xT[64][CC + 8];

    {
        const float* xb = x + (size_t)b * CC * TT;
        const int tq = tid & 7;
        const int cp = tid >> 3;
        #pragma unroll
        for (int pass = 0; pass < 6; ++pass) {
            const int c = (pass * 32 + cp) * 2;
            const float* r0 = xb + (size_t)c * TT + t0 + tq * 8;
            const float* r1 = r0 + TT;
            f32x4 a0 = *(const f32x4*)r0, a1 = *(const f32x4*)(r0 + 4);
            f32x4 b0 = *(const f32x4*)r1, b1 = *(const f32x4*)(r1 + 4);
            #pragma unroll
            for (int j = 0; j < 8; ++j) {
                U2 p;
                p.h[0] = (bf16_t)((j < 4) ? a0[j] : a1[j - 4]);
                p.h[1] = (bf16_t)((j < 4) ? b0[j] : b1[j - 4]);
                *(unsigned int*)&xT[tq * 8 + j][c] = p.u;
            }
        }
    }
    __syncthreads();

    const bf16_t* W = (og < 2) ? Wq : (og < 4) ? Wk : Wv;
    const int obase = (og & 1) * 192 + wid * 48;

    if (og < 4) {
        f32x4 acc[3][4];
        const f32x4 zero = {0.f, 0.f, 0.f, 0.f};
        #pragma unroll
        for (int mi = 0; mi < 3; ++mi)
            #pragma unroll
            for (int ni = 0; ni < 4; ++ni) acc[mi][ni] = zero;

        for (int k0 = 0; k0 < CC; k0 += 32) {
            bf16x8 afr[3];
            #pragma unroll
            for (int mi = 0; mi < 3; ++mi)
                afr[mi] = *(const bf16x8*)(W + (size_t)(obase + mi * 16 + l16) * CC + k0 + quad * 8);
            #pragma unroll
            for (int ni = 0; ni < 4; ++ni) {
                bf16x8 bfr = *(const bf16x8*)&xT[ni * 16 + l16][k0 + quad * 8];
                #pragma unroll
                for (int mi = 0; mi < 3; ++mi)
                    acc[mi][ni] = MFMA16(afr[mi], bfr, acc[mi][ni]);
            }
        }

        bf16_t* dst = (og < 2) ? qT : kT;
        #pragma unroll
        for (int mi = 0; mi < 3; ++mi)
            #pragma unroll
            for (int ni = 0; ni < 4; ++ni) {
                const int o0 = obase + mi * 16 + quad * 4;
                const int tl = t0 + ni * 16 + l16;
                U2 lo2, hi2;
                lo2.h[0] = (bf16_t)acc[mi][ni][0]; lo2.h[1] = (bf16_t)acc[mi][ni][1];
                hi2.h[0] = (bf16_t)acc[mi][ni][2]; hi2.h[1] = (bf16_t)acc[mi][ni][3];
                uint2 pk; pk.x = lo2.u; pk.y = hi2.u;
                *(uint2*)(dst + ((size_t)b * TT + tl) * CC + o0) = pk;
            }
    } else {
        f32x4 acc[4][3];
        const f32x4 zero = {0.f, 0.f, 0.f, 0.f};
        #pragma unroll
        for (int mi = 0; mi < 4; ++mi)
            #pragma unroll
            for (int ni = 0; ni < 3; ++ni) acc[mi][ni] = zero;

        for (int k0 = 0; k0 < CC; k0 += 32) {
            bf16x8 bfr[3];
            #pragma unroll
            for (int ni = 0; ni < 3; ++ni)
                bfr[ni] = *(const bf16x8*)(W + (size_t)(obase + ni * 16 + l16) * CC + k0 + quad * 8);
            #pragma unroll
            for (int mi = 0; mi < 4; ++mi) {
                bf16x8 afr = *(const bf16x8*)&xT[mi * 16 + l16][k0 + quad * 8];
                #pragma unroll
                for (int ni = 0; ni < 3; ++ni)
                    acc[mi][ni] = MFMA16(afr, bfr[ni], acc[mi][ni]);
            }
        }

        #pragma unroll
        for (int mi = 0; mi < 4; ++mi)
            #pragma unroll
            for (int ni = 0; ni < 3; ++ni) {
                const int ol  = obase + ni * 16 + l16;
                const int tl0 = mi * 16 + quad * 4;
                U2 lo2, hi2;
                lo2.h[0] = (bf16_t)acc[mi][ni][0]; lo2.h[1] = (bf16_t)acc[mi][ni][1];
                hi2.h[0] = (bf16_t)acc[mi][ni][2]; hi2.h[1] = (bf16_t)acc[mi][ni][3];
                uint2 pk; pk.x = lo2.u; pk.y = hi2.u;
                *(uint2*)(vm + ((size_t)b * CC + ol) * TT + t0 + tl0) = pk;
            }

        // vrow partial: sum over this tile's 64 t per o
        #pragma unroll
        for (int ni = 0; ni < 3; ++ni) {
            float s = 0.f;
            #pragma unroll
            for (int mi = 0; mi < 4; ++mi)
                #pragma unroll
                for (int r = 0; r < 4; ++r) s += acc[mi][ni][r];
            s += __shfl_xor(s, 16, 64);
            s += __shfl_xor(s, 32, 64);
            if (quad == 0)
                vrp[((size_t)tt * 8 + b) * CC + obase + ni * 16 + l16] = s;
        }
    }
}

// ---------------------------------------------------------------------------
// K2: fused attention. Round-11 restructure:
//  - NO V LDS: PV B-fragments read DIRECT from vm (L2-resident per XCD,
//    16 B/lane). Removes V staging + its barrier dependency.
//  - LDS = K double-buffer only (48 KB). K(t+1) issued at tile TOP into the
//    other buffer -> has the ENTIRE tile (scores+mix+PV) to land.
//  - ONE barrier per tile (protects K buffer swap + drains prefetch).
// Grid 512 = 8 b (XCD) x 16 qt x 4 tq. 256 thr / 4 waves, no spill.
// Per-wave math (scores, SGPR mix, bpermute transpose, PV) unchanged.
// ---------------------------------------------------------------------------
__global__ __launch_bounds__(256, 1) void fused_attn(
    const bf16_t* __restrict__ qT,
    const bf16_t* __restrict__ kT,
    const bf16_t* __restrict__ vm,
    const float*  __restrict__ head_w,
    float* __restrict__ Up,      // [4][8][6][1024][64]
    float* __restrict__ lp,      // [4][48][1024]
    float* __restrict__ l2p)     // [4][48][1024]
{
    const int L  = blockIdx.x;
    const int b  = L & 7;              // XCD-pinned
    const int rr = L >> 3;
    const int qt = rr & 15;            // 0..15 (64-q tile)
    const int tq = rr >> 4;            // 0..3  (256-t quarter)
    const int T0 = tq * 256;
    const int stag = (rr & 1) * 4;     // de-phase co-resident blocks

    const int tid = threadIdx.x, lane = tid & 63, wid = tid >> 6;
    const int quad = lane >> 4, l16 = lane & 15;

    __shared__ __align__(16) bf16_t sm[24576];   // 48 KB: Ks0 | Ks1 (2 x 24 KB)
    const int  s3    = l16 & 7;
    const int  addrA = ((quad & 1) * 32 + l16) * 4;
    const int  addrB = addrA + 64;
    const bool qlo   = (quad < 2);

    // mix coefficients -> SGPRs
    float mixc[36];
    #pragma unroll
    for (int j = 0; j < 36; ++j) {
        const float v = 0.125f * head_w[j];
        mixc[j] = __uint_as_float(__builtin_amdgcn_readfirstlane(__float_as_uint(v)));
    }

    // persistent Q fragments: rows q = qt*64 + wid*16 + l16
    bf16x8 qf[6][2];
    {
        const bf16_t* qp = qT + ((size_t)b * TT + qt * 64 + wid * 16 + l16) * CC + quad * 8;
        #pragma unroll
        for (int h = 0; h < 6; ++h)
            #pragma unroll
            for (int k2 = 0; k2 < 2; ++k2)
                qf[h][k2] = *(const bf16x8*)(qp + h * 64 + k2 * 32);
    }

    // K staging: pre-swizzled global src, linear LDS dst. 1536 chunks/buf.
    int koff[6];
    #pragma unroll
    for (int i = 0; i < 6; ++i) {
        const int f = i * 256 + tid;
        const int krow = f / 48, kc = f - krow * 48;           // Ks: 32 rows x 48 chunks
        koff[i] = krow * CC + ((kc & 56) | ((kc ^ krow) & 7)) * 8;
    }
    const bf16_t* kTb = kT + ((size_t)b * TT + T0) * CC;
    const bf16_t* vmb = vm + (size_t)b * CC * TT + T0;
    char* KsB = (char*)sm;             // Ks buf p at byte p*24576
    const int ldst = tid * 16;

    // prologue: stage K(lt=stag) into buf 0
    #pragma unroll
    for (int i = 0; i < 6; ++i)
        gload_lds16(kTb + (size_t)stag * 32 * CC + koff[i], KsB + i * 4096 + ldst);

    f32x4 U[6][4];
    const f32x4 zero = {0.f, 0.f, 0.f, 0.f};
    #pragma unroll
    for (int h = 0; h < 6; ++h)
        #pragma unroll
        for (int d = 0; d < 4; ++d) U[h][d] = zero;
    float lacc[6]  = {0.f, 0.f, 0.f, 0.f, 0.f, 0.f};
    float l2acc[6] = {0.f, 0.f, 0.f, 0.f, 0.f, 0.f};

    __syncthreads();   // K buf0 staged

    for (int it = 0; it < 8; ++it) {
        const int lt = (it + stag) & 7;    // logical tile (exact sum: any order)
        const int cb = it & 1;             // current K buffer

        // ---- issue K(next) at tile top -> other buffer (whole tile to land)
        if (it < 7) {
            const int ltn = (lt + 1) & 7;
            #pragma unroll
            for (int i = 0; i < 6; ++i)
                gload_lds16(kTb + (size_t)ltn * 32 * CC + koff[i],
                            KsB + (cb ^ 1) * 24576 + i * 4096 + ldst);
        }

        // ---- per-head scores: lane (q = l16, t = blk*16 + quad*4 + r)
        const bf16_t* Kc = sm + cb * 12288;
        f32x4 S[6][2];
        __builtin_amdgcn_s_setprio(1);
        #pragma unroll
        for (int h = 0; h < 6; ++h) {
            #pragma unroll
            for (int blk = 0; blk < 2; ++blk) {
                const bf16_t* Ar = Kc + (size_t)(blk * 16 + l16) * CC + h * 64;
                bf16x8 a0 = *(const bf16x8*)(Ar + ((quad ^ s3) * 8));
                bf16x8 a1 = *(const bf16x8*)(Ar + (((4 + quad) ^ s3) * 8));
                f32x4 s = MFMA16(a0, qf[h][0], zero);
                S[h][blk] = MFMA16(a1, qf[h][1], s);
            }
        }
        __builtin_amdgcn_s_setprio(0);

        // ---- mix + exp + l/l2 + intra-wave transpose -> PV A-frags
        bf16x8 pa[6];
        #pragma unroll
        for (int g = 0; g < 6; ++g) {
            unsigned int uu[2][2];
            #pragma unroll
            for (int blk = 0; blk < 2; ++blk) {
                f32x4 m = mixc[g * 6] * S[0][blk];
                #pragma unroll
                for (int h2 = 1; h2 < 6; ++h2) m += mixc[g * 6 + h2] * S[h2][blk];
                f32x4 pv;
                #pragma unroll
                for (int r = 0; r < 4; ++r) pv[r] = __expf(fminf(m[r], 60.0f));
                lacc[g]  += pv[0] + pv[1] + pv[2] + pv[3];
                l2acc[g] += pv[0] * pv[0] + pv[1] * pv[1] + pv[2] * pv[2] + pv[3] * pv[3];
                U2 lo, hi;
                lo.h[0] = (bf16_t)pv[0]; lo.h[1] = (bf16_t)pv[1];
                hi.h[0] = (bf16_t)pv[2]; hi.h[1] = (bf16_t)pv[3];
                uu[blk][0] = lo.u; uu[blk][1] = hi.u;
            }
            int x0 = __builtin_amdgcn_ds_bpermute(addrA, (int)uu[0][0]);
            int y0 = __builtin_amdgcn_ds_bpermute(addrA, (int)uu[1][0]);
            int x1 = __builtin_amdgcn_ds_bpermute(addrA, (int)uu[0][1]);
            int y1 = __builtin_amdgcn_ds_bpermute(addrA, (int)uu[1][1]);
            int x2 = __builtin_amdgcn_ds_bpermute(addrB, (int)uu[0][0]);
            int y2 = __builtin_amdgcn_ds_bpermute(addrB, (int)uu[1][0]);
            int x3 = __builtin_amdgcn_ds_bpermute(addrB, (int)uu[0][1]);
            int y3 = __builtin_amdgcn_ds_bpermute(addrB, (int)uu[1][1]);
            I4B c;
            c.i = (i32x4){qlo ? x0 : y0, qlo ? x1 : y1, qlo ? x2 : y2, qlo ? x3 : y3};
            pa[g] = c.v;
        }

        // ---- PV: B-fragments direct from vm (L2). Lane: n = n2*16+l16 (d),
        //      k = quad*8+j (t_local). No barrier between mix and PV.
        __builtin_amdgcn_s_setprio(1);
        #pragma unroll
        for (int h = 0; h < 6; ++h) {
            #pragma unroll
            for (int n2 = 0; n2 < 4; ++n2) {
                bf16x8 bv = *(const bf16x8*)(vmb
                    + (size_t)(h * 64 + n2 * 16 + l16) * TT + lt * 32 + quad * 8);
                U[h][n2] = MFMA16(pa[h], bv, U[h][n2]);
            }
        }
        __builtin_amdgcn_s_setprio(0);

        __syncthreads();   // single barrier: K(next) drained; Ks[cb] reads done
    }

    // ---- epilogue: direct per-wave outputs
    #pragma unroll
    for (int g = 0; g < 6; ++g) {
        float l = lacc[g], l2 = l2acc[g];
        l  += __shfl_xor(l, 16, 64);  l  += __shfl_xor(l, 32, 64);
        l2 += __shfl_xor(l2, 16, 64); l2 += __shfl_xor(l2, 32, 64);
        if (quad == 0) {
            const size_t o = ((size_t)tq * 48 + b * 6 + g) * TT + qt * 64 + wid * 16 + l16;
            lp[o] = l; l2p[o] = l2;
        }
    }

    #pragma unroll
    for (int h = 0; h < 6; ++h) {
        float* Ub = Up + ((((size_t)tq * 8 + b) * 6 + h) * TT + qt * 64 + wid * 16) * 64;
        #pragma unroll
        for (int n2 = 0; n2 < 4; ++n2)
            #pragma unroll
            for (int r = 0; r < 4; ++r)
                Ub[(size_t)(quad * 4 + r) * 64 + n2 * 16 + l16] = U[h][n2][r];
    }
}

// ---------------------------------------------------------------------------
// K2b: stats, 48 blocks x 1024 thr (no atomics, no memsets):
//   linv[bg][q] = 1/sum_p lp[p][bg][q];  sq[bg] = sum_q l2/l^2
//   vr[b][g*64+d] = sum_tt vrp[tt][b][g*64+d]   (16 tile partials)
// ---------------------------------------------------------------------------
__global__ __launch_bounds__(1024) void stats_kernel(
    const float* __restrict__ lp, const float* __restrict__ l2p,
    const float* __restrict__ vrp,
    float* __restrict__ linv, float* __restrict__ sq, float* __restrict__ vr)
{
    const int bg = blockIdx.x, tid = threadIdx.x;
    const int b = bg / 6, g = bg - b * 6;

    __shared__ float red[16];
    __shared__ float vred[8][64];

    const int q = tid;
    const float l  = lp [(size_t)bg * TT + q] + lp [(size_t)(48 + bg) * TT + q]
                   + lp [(size_t)(96 + bg) * TT + q] + lp [(size_t)(144 + bg) * TT + q];
    const float l2 = l2p[(size_t)bg * TT + q] + l2p[(size_t)(48 + bg) * TT + q]
                   + l2p[(size_t)(96 + bg) * TT + q] + l2p[(size_t)(144 + bg) * TT + q];
    const float inv = 1.0f / l;
    linv[bg * TT + q] = inv;
    float c = l2 * inv * inv;
    #pragma unroll
    for (int off = 1; off < 64; off <<= 1) c += __shfl_xor(c, off, 64);
    if ((tid & 63) == 0) red[tid >> 6] = c;

    if (tid < 512) {
        const int d = tid & 63, ck = tid >> 6;   // 8 chunks x 2 tiles
        float s = 0.f;
        #pragma unroll
        for (int t2 = 0; t2 < 2; ++t2) {
            const int t = ck * 2 + t2;
            s += vrp[((size_t)t * 8 + b) * CC + g * 64 + d];
        }
        vred[ck][d] = s;
    }
    __syncthreads();
    if (tid == 0) {
        float s = 0.f;
        #pragma unroll
        for (int k = 0; k < 16; ++k) s += red[k];
        sq[bg] = s;
    }
    if (tid < 64) {
        float s = 0.f;
        #pragma unroll
        for (int k = 0; k < 8; ++k) s += vred[k][tid];
        vr[b * CC + g * 64 + tid] = s;
    }
}

// ---------------------------------------------------------------------------
// K3: projection + fused InstanceNorm affine + bias + transpose.
// bf16 projW, cached partial loads (L3), unroll-2 k-loop.
// Grid (64,8): 16-t tiles -> 512 blocks = 2 blocks/CU.
// ---------------------------------------------------------------------------
__global__ __launch_bounds__(256) void proj_kernel(
    const float* __restrict__ Up,
    const float* __restrict__ linv,
    const float* __restrict__ vrs,
    const float* __restrict__ sumsq,
    const float* __restrict__ gamma,
    const float* __restrict__ beta,
    const bf16_t* __restrict__ projW,
    const float* __restrict__ projb,
    float* __restrict__ out)
{
    const int ts = blockIdx.x;
    const int b  = blockIdx.y;
    const int t0 = ts * 16;
    const int tid = threadIdx.x, lane = tid & 63, wid = tid >> 6;
    const int quad = lane >> 4, l16 = lane & 15;

    __shared__ float Ac[6], Cc[6], pb[CC];
    if (tid < 6) {
        const float ss  = sumsq[b * NHH + tid];
        const float var = fmaxf(ss - 1.0f, 0.0f) * (1.0f / 1048576.0f);
        const float a   = gamma[tid] * rsqrtf(var + 1e-5f);
        Ac[tid] = a;
        Cc[tid] = beta[tid] - a * (1.0f / 1024.0f);
    }
    for (int i = tid; i < CC; i += 256) pb[i] = projb[i];
    __syncthreads();

    f32x4 acc[6];
    const f32x4 zero = {0.f, 0.f, 0.f, 0.f};
    #pragma unroll
    for (int mi = 0; mi < 6; ++mi) acc[mi] = zero;

    constexpr size_t PST = (size_t)BB * NHH * TT * 64;
    const float* Ub = Up + (size_t)b * (NHH * TT * 64);
    #pragma unroll 2
    for (int k0 = 0; k0 < CC; k0 += 32) {
        const int tl = t0 + l16;
        const int baseoff = tl * CC + k0 + quad * 8;
        const int hh = baseoff >> 16;                 // constant over j (8-aligned)
        const int d0 = baseoff & 63;                  // d of j=0; d0+7 <= 63
        const float li = linv[b * 6144 + (baseoff >> 6)];
        const float Al = Ac[hh] * li;
        const float Cb = Cc[hh];
        f32x4 u0 = *(const f32x4*)(Ub + baseoff)
                 + *(const f32x4*)(Ub + PST + baseoff)
                 + *(const f32x4*)(Ub + 2 * PST + baseoff)
                 + *(const f32x4*)(Ub + 3 * PST + baseoff);
        f32x4 u1 = *(const f32x4*)(Ub + baseoff + 4)
                 + *(const f32x4*)(Ub + PST + baseoff + 4)
                 + *(const f32x4*)(Ub + 2 * PST + baseoff + 4)
                 + *(const f32x4*)(Ub + 3 * PST + baseoff + 4);
        U8 z;
        #pragma unroll
        for (int j = 0; j < 8; ++j) {
            const float uv = (j < 4) ? u0[j] : u1[j - 4];
            z.h[j] = (bf16_t)(Al * uv + Cb * vrs[b * CC + hh * 64 + d0 + j]);
        }
        bf16x8 bfr = *(const bf16x8*)&z;
        #pragma unroll
        for (int mi = 0; mi < 6; ++mi) {
            const int o = wid * 96 + mi * 16 + l16;
            bf16x8 afr = *(const bf16x8*)(projW + (size_t)o * CC + k0 + quad * 8);
            acc[mi] = MFMA16(afr, bfr, acc[mi]);
        }
    }

    #pragma unroll
    for (int mi = 0; mi < 6; ++mi)
        #pragma unroll
        for (int r = 0; r < 4; ++r) {
            const int o  = wid * 96 + mi * 16 + quad * 4 + r;
            const int tl = t0 + l16;
            out[((size_t)b * CC + o) * TT + tl] = acc[mi][r] + pb[o];
        }
}

// ---------------------------------------------------------------------------
extern "C" void kernel_launch(void* const* d_in, const int* in_sizes, int n_in,
                              void* d_out, int out_size, void* d_ws, size_t ws_size,
                              hipStream_t stream)
{
    float* outp = (float*)d_out;
    char* ws = (char*)d_ws;

    size_t off = 0;
    auto alloc = [&](size_t bytes) {
        void* p = ws + off;
        off += (bytes + 255) & ~(size_t)255;
        return p;
    };

    const size_t szT = (size_t)BB * TT * CC * sizeof(bf16_t);   // 6.29 MB
    const size_t szW = (size_t)CC * CC * sizeof(bf16_t);        // 288 KB

    bf16_t* qTb = (bf16_t*)alloc(szT);
    bf16_t* kTb = (bf16_t*)alloc(szT);
    bf16_t* vmb = (bf16_t*)alloc(szT);
    bf16_t* Wqb = (bf16_t*)alloc(szW);
    bf16_t* Wkb = (bf16_t*)alloc(szW);
    bf16_t* Wvb = (bf16_t*)alloc(szW);
    bf16_t* PWb = (bf16_t*)alloc(szW);
    float*  Uh  = (float*)alloc((size_t)4 * BB * NHH * TT * 64 * sizeof(float)); // 50.3 MB
    float*  lpb = (float*)alloc((size_t)4 * 48 * TT * sizeof(float));
    float*  l2b = (float*)alloc((size_t)4 * 48 * TT * sizeof(float));
    float*  lv  = (float*)alloc((size_t)48 * TT * sizeof(float));
    float*  vrp = (float*)alloc((size_t)16 * BB * CC * sizeof(float));
    float*  vr  = (float*)alloc((size_t)BB * CC * sizeof(float));
    float*  sq  = (float*)alloc(48 * sizeof(float));

    castw_kernel<<<dim3(72, 4), 256, 0, stream>>>(
        (const float*)d_in[1], (const float*)d_in[2], (const float*)d_in[3],
        (const float*)d_in[7], Wqb, Wkb, Wvb, PWb);
    qkv_kernel<<<dim3(16, 6, 8), 256, 0, stream>>>(
        (const float*)d_in[0], Wqb, Wkb, Wvb, qTb, kTb, vmb, vrp);
    fused_attn<<<512, 256, 0, stream>>>(
        qTb, kTb, vmb, (const float*)d_in[4], Uh, lpb, l2b);
    stats_kernel<<<48, 1024, 0, stream>>>(lpb, l2b, vrp, lv, sq, vr);
    proj_kernel<<<dim3(64, 8), 256, 0, stream>>>(
        Uh, lv, vr, sq, (const float*)d_in[5], (const float*)d_in[6],
        PWb, (const float*)d_in[8], outp);
}

// Round 12
// 206.153 us; speedup vs baseline: 1.2351x; 1.2351x over previous
//
#include <hip/hip_runtime.h>
#include <hip/hip_bf16.h>
#include <cstdint>

typedef __bf16 bf16_t;
typedef __bf16 bf16x8 __attribute__((ext_vector_type(8)));
typedef float  f32x4  __attribute__((ext_vector_type(4)));
typedef int    i32x4  __attribute__((ext_vector_type(4)));

#define MFMA16(a, b, c) __builtin_amdgcn_mfma_f32_16x16x32_bf16((a), (b), (c), 0, 0, 0)

constexpr int BB = 8, CC = 384, NHH = 6, TT = 1024;

union U8 { uint4 u; bf16_t h[8]; };
union U2 { unsigned int u; bf16_t h[2]; };
union I4B { i32x4 i; bf16x8 v; };

static __device__ __forceinline__ void gload_lds16(const void* g, void* l) {
    __builtin_amdgcn_global_load_lds((const __attribute__((address_space(1))) void*)g,
                                     (__attribute__((address_space(3))) void*)l, 16, 0, 0);
}

// ---------------------------------------------------------------------------
// K0: one-shot weight cast fp32 -> bf16 (Wq, Wk, Wv, projW).
// ---------------------------------------------------------------------------
__global__ __launch_bounds__(256) void castw_kernel(
    const float* __restrict__ w0, const float* __restrict__ w1,
    const float* __restrict__ w2, const float* __restrict__ w3,
    bf16_t* __restrict__ d0, bf16_t* __restrict__ d1,
    bf16_t* __restrict__ d2, bf16_t* __restrict__ d3)
{
    const int wi = blockIdx.y;
    const float* s = (wi == 0) ? w0 : (wi == 1) ? w1 : (wi == 2) ? w2 : w3;
    bf16_t*      d = (wi == 0) ? d0 : (wi == 1) ? d1 : (wi == 2) ? d2 : d3;
    const int idx = (blockIdx.x * 256 + threadIdx.x) * 8;
    f32x4 a = *(const f32x4*)(s + idx);
    f32x4 b = *(const f32x4*)(s + idx + 4);
    U8 o;
    #pragma unroll
    for (int j = 0; j < 4; ++j) { o.h[j] = (bf16_t)a[j]; o.h[4 + j] = (bf16_t)b[j]; }
    *(uint4*)(d + idx) = o.u;
}

// ---------------------------------------------------------------------------
// K1: QKV projection — round-9 shape (t-tile 64, best measured), bf16 weights,
// fp32 x cast during staging. v-branch writes vrp[tt][b][o] partials
// (memset-free). Grid dim3(16,6,8): 6 og-blocks of one (b,tt) share an XCD.
// ---------------------------------------------------------------------------
__global__ __launch_bounds__(256) void qkv_kernel(
    const float* __restrict__ x,
    const bf16_t* __restrict__ Wq,
    const bf16_t* __restrict__ Wk,
    const bf16_t* __restrict__ Wv,
    bf16_t* __restrict__ qT,
    bf16_t* __restrict__ kT,
    bf16_t* __restrict__ vm,
    float*  __restrict__ vrp)    // [16][8][384]
{
    const int tt = blockIdx.x;
    const int og = blockIdx.y;        // 0,1:q  2,3:k  4,5:v  (og&1 = o-half)
    const int b  = blockIdx.z;
    const int t0 = tt * 64;
    const int tid  = threadIdx.x;
    const int lane = tid & 63;
    const int wid  = tid >> 6;
    const int quad = lane >> 4;
    const int l16  = lane & 15;

    __shared__ __align__(16) bf16_t xT[64][CC + 8];

    {
        const float* xb = x + (size_t)b * CC * TT;
        const int tq = tid & 7;
        const int cp = tid >> 3;
        #pragma unroll
        for (int pass = 0; pass < 6; ++pass) {
            const int c = (pass * 32 + cp) * 2;
            const float* r0 = xb + (size_t)c * TT + t0 + tq * 8;
            const float* r1 = r0 + TT;
            f32x4 a0 = *(const f32x4*)r0, a1 = *(const f32x4*)(r0 + 4);
            f32x4 b0 = *(const f32x4*)r1, b1 = *(const f32x4*)(r1 + 4);
            #pragma unroll
            for (int j = 0; j < 8; ++j) {
                U2 p;
                p.h[0] = (bf16_t)((j < 4) ? a0[j] : a1[j - 4]);
                p.h[1] = (bf16_t)((j < 4) ? b0[j] : b1[j - 4]);
                *(unsigned int*)&xT[tq * 8 + j][c] = p.u;
            }
        }
    }
    __syncthreads();

    const bf16_t* W = (og < 2) ? Wq : (og < 4) ? Wk : Wv;
    const int obase = (og & 1) * 192 + wid * 48;

    if (og < 4) {
        f32x4 acc[3][4];
        const f32x4 zero = {0.f, 0.f, 0.f, 0.f};
        #pragma unroll
        for (int mi = 0; mi < 3; ++mi)
            #pragma unroll
            for (int ni = 0; ni < 4; ++ni) acc[mi][ni] = zero;

        for (int k0 = 0; k0 < CC; k0 += 32) {
            bf16x8 afr[3];
            #pragma unroll
            for (int mi = 0; mi < 3; ++mi)
                afr[mi] = *(const bf16x8*)(W + (size_t)(obase + mi * 16 + l16) * CC + k0 + quad * 8);
            #pragma unroll
            for (int ni = 0; ni < 4; ++ni) {
                bf16x8 bfr = *(const bf16x8*)&xT[ni * 16 + l16][k0 + quad * 8];
                #pragma unroll
                for (int mi = 0; mi < 3; ++mi)
                    acc[mi][ni] = MFMA16(afr[mi], bfr, acc[mi][ni]);
            }
        }

        bf16_t* dst = (og < 2) ? qT : kT;
        #pragma unroll
        for (int mi = 0; mi < 3; ++mi)
            #pragma unroll
            for (int ni = 0; ni < 4; ++ni) {
                const int o0 = obase + mi * 16 + quad * 4;
                const int tl = t0 + ni * 16 + l16;
                U2 lo2, hi2;
                lo2.h[0] = (bf16_t)acc[mi][ni][0]; lo2.h[1] = (bf16_t)acc[mi][ni][1];
                hi2.h[0] = (bf16_t)acc[mi][ni][2]; hi2.h[1] = (bf16_t)acc[mi][ni][3];
                uint2 pk; pk.x = lo2.u; pk.y = hi2.u;
                *(uint2*)(dst + ((size_t)b * TT + tl) * CC + o0) = pk;
            }
    } else {
        f32x4 acc[4][3];
        const f32x4 zero = {0.f, 0.f, 0.f, 0.f};
        #pragma unroll
        for (int mi = 0; mi < 4; ++mi)
            #pragma unroll
            for (int ni = 0; ni < 3; ++ni) acc[mi][ni] = zero;

        for (int k0 = 0; k0 < CC; k0 += 32) {
            bf16x8 bfr[3];
            #pragma unroll
            for (int ni = 0; ni < 3; ++ni)
                bfr[ni] = *(const bf16x8*)(W + (size_t)(obase + ni * 16 + l16) * CC + k0 + quad * 8);
            #pragma unroll
            for (int mi = 0; mi < 4; ++mi) {
                bf16x8 afr = *(const bf16x8*)&xT[mi * 16 + l16][k0 + quad * 8];
                #pragma unroll
                for (int ni = 0; ni < 3; ++ni)
                    acc[mi][ni] = MFMA16(afr, bfr[ni], acc[mi][ni]);
            }
        }

        #pragma unroll
        for (int mi = 0; mi < 4; ++mi)
            #pragma unroll
            for (int ni = 0; ni < 3; ++ni) {
                const int ol  = obase + ni * 16 + l16;
                const int tl0 = mi * 16 + quad * 4;
                U2 lo2, hi2;
                lo2.h[0] = (bf16_t)acc[mi][ni][0]; lo2.h[1] = (bf16_t)acc[mi][ni][1];
                hi2.h[0] = (bf16_t)acc[mi][ni][2]; hi2.h[1] = (bf16_t)acc[mi][ni][3];
                uint2 pk; pk.x = lo2.u; pk.y = hi2.u;
                *(uint2*)(vm + ((size_t)b * CC + ol) * TT + t0 + tl0) = pk;
            }

        // vrow partial: sum over this tile's 64 t per o
        #pragma unroll
        for (int ni = 0; ni < 3; ++ni) {
            float s = 0.f;
            #pragma unroll
            for (int mi = 0; mi < 4; ++mi)
                #pragma unroll
                for (int r = 0; r < 4; ++r) s += acc[mi][ni][r];
            s += __shfl_xor(s, 16, 64);
            s += __shfl_xor(s, 32, 64);
            if (quad == 0)
                vrp[((size_t)tt * 8 + b) * CC + obase + ni * 16 + l16] = s;
        }
    }
}

// ---------------------------------------------------------------------------
// K2: fused attention — round-9 structure (best measured: 68.5 us), with the
// STAGGER FIX: co-resident block pairs are (L, L+256) (512 blocks round-robin
// over 256 CUs); rr differs by 32 so (rr&1) gave IDENTICAL phase -> round-9's
// stagger was a no-op. stag = ((L>>8)&1)*4 de-phases the actual pairs.
// LDS 72 KB: Ks double-buffer (2x24K) + Vs 24K. V(lt)+K(next) issued at tile
// top; B1 after mix drains them; PV from Vs; B2 protects Vs reuse.
// ---------------------------------------------------------------------------
__global__ __launch_bounds__(256, 1) void fused_attn(
    const bf16_t* __restrict__ qT,
    const bf16_t* __restrict__ kT,
    const bf16_t* __restrict__ vm,
    const float*  __restrict__ head_w,
    float* __restrict__ Up,      // [4][8][6][1024][64]
    float* __restrict__ lp,      // [4][48][1024]
    float* __restrict__ l2p)     // [4][48][1024]
{
    const int L  = blockIdx.x;
    const int b  = L & 7;              // XCD-pinned
    const int rr = L >> 3;
    const int qt = rr & 15;            // 0..15 (64-q tile)
    const int tq = rr >> 4;            // 0..3  (256-t quarter)
    const int T0 = tq * 256;
    const int stag = ((L >> 8) & 1) * 4;   // de-phase co-resident pairs (L, L+256)

    const int tid = threadIdx.x, lane = tid & 63, wid = tid >> 6;
    const int quad = lane >> 4, l16 = lane & 15;

    __shared__ __align__(16) bf16_t sm[36864];   // 72 KB: Ks0|Ks1 (2x24K) | Vs 24K
    const int  s3    = l16 & 7;
    const int  vswz  = (quad ^ ((l16 >> 1) & 3)) * 8;
    const int  addrA = ((quad & 1) * 32 + l16) * 4;
    const int  addrB = addrA + 64;
    const bool qlo   = (quad < 2);

    // mix coefficients -> SGPRs
    float mixc[36];
    #pragma unroll
    for (int j = 0; j < 36; ++j) {
        const float v = 0.125f * head_w[j];
        mixc[j] = __uint_as_float(__builtin_amdgcn_readfirstlane(__float_as_uint(v)));
    }

    // persistent Q fragments: rows q = qt*64 + wid*16 + l16
    bf16x8 qf[6][2];
    {
        const bf16_t* qp = qT + ((size_t)b * TT + qt * 64 + wid * 16 + l16) * CC + quad * 8;
        #pragma unroll
        for (int h = 0; h < 6; ++h)
            #pragma unroll
            for (int k2 = 0; k2 < 2; ++k2)
                qf[h][k2] = *(const bf16x8*)(qp + h * 64 + k2 * 32);
    }

    // staging: pre-swizzled global src, linear LDS dst. 1536 chunks per buf.
    int koff[6], voff[6];
    #pragma unroll
    for (int i = 0; i < 6; ++i) {
        const int f = i * 256 + tid;
        const int krow = f / 48, kc = f - krow * 48;           // Ks: 32 rows x 48 chunks
        koff[i] = krow * CC + ((kc & 56) | ((kc ^ krow) & 7)) * 8;
        const int vrow = f >> 2, vc = f & 3;                   // Vs: 384 rows x 4 chunks
        voff[i] = vrow * TT + ((vc ^ ((vrow >> 1) & 3)) * 8);
    }
    const bf16_t* kTb = kT + ((size_t)b * TT + T0) * CC;
    const bf16_t* vmb = vm + (size_t)b * CC * TT + T0;
    char* KsB = (char*)sm;             // Ks buf p at byte p*24576
    char* VsB = (char*)sm + 49152;     // elem offset 24576
    const int ldst = tid * 16;

    // prologue: stage K(lt=stag) into buf 0
    #pragma unroll
    for (int i = 0; i < 6; ++i)
        gload_lds16(kTb + (size_t)stag * 32 * CC + koff[i], KsB + i * 4096 + ldst);

    f32x4 U[6][4];
    const f32x4 zero = {0.f, 0.f, 0.f, 0.f};
    #pragma unroll
    for (int h = 0; h < 6; ++h)
        #pragma unroll
        for (int d = 0; d < 4; ++d) U[h][d] = zero;
    float lacc[6]  = {0.f, 0.f, 0.f, 0.f, 0.f, 0.f};
    float l2acc[6] = {0.f, 0.f, 0.f, 0.f, 0.f, 0.f};

    __syncthreads();   // K buf0 staged

    for (int it = 0; it < 8; ++it) {
        const int lt = (it + stag) & 7;    // logical tile (exact sum: any order)
        const int cb = it & 1;             // current K buffer

        // ---- issue V(lt) and K(next) at tile top (both land during scores+mix)
        #pragma unroll
        for (int i = 0; i < 6; ++i)
            gload_lds16(vmb + lt * 32 + voff[i], VsB + i * 4096 + ldst);
        if (it < 7) {
            const int ltn = (lt + 1) & 7;
            #pragma unroll
            for (int i = 0; i < 6; ++i)
                gload_lds16(kTb + (size_t)ltn * 32 * CC + koff[i],
                            KsB + (cb ^ 1) * 24576 + i * 4096 + ldst);
        }

        // ---- per-head scores: lane (q = l16, t = blk*16 + quad*4 + r)
        const bf16_t* Kc = sm + cb * 12288;
        f32x4 S[6][2];
        __builtin_amdgcn_s_setprio(1);
        #pragma unroll
        for (int h = 0; h < 6; ++h) {
            #pragma unroll
            for (int blk = 0; blk < 2; ++blk) {
                const bf16_t* Ar = Kc + (size_t)(blk * 16 + l16) * CC + h * 64;
                bf16x8 a0 = *(const bf16x8*)(Ar + ((quad ^ s3) * 8));
                bf16x8 a1 = *(const bf16x8*)(Ar + (((4 + quad) ^ s3) * 8));
                f32x4 s = MFMA16(a0, qf[h][0], zero);
                S[h][blk] = MFMA16(a1, qf[h][1], s);
            }
        }
        __builtin_amdgcn_s_setprio(0);

        // ---- mix + exp + l/l2 + intra-wave transpose -> PV A-frags
        bf16x8 pa[6];
        #pragma unroll
        for (int g = 0; g < 6; ++g) {
            unsigned int uu[2][2];
            #pragma unroll
            for (int blk = 0; blk < 2; ++blk) {
                f32x4 m = mixc[g * 6] * S[0][blk];
                #pragma unroll
                for (int h2 = 1; h2 < 6; ++h2) m += mixc[g * 6 + h2] * S[h2][blk];
                f32x4 pv;
                #pragma unroll
                for (int r = 0; r < 4; ++r) pv[r] = __expf(fminf(m[r], 60.0f));
                lacc[g]  += pv[0] + pv[1] + pv[2] + pv[3];
                l2acc[g] += pv[0] * pv[0] + pv[1] * pv[1] + pv[2] * pv[2] + pv[3] * pv[3];
                U2 lo, hi;
                lo.h[0] = (bf16_t)pv[0]; lo.h[1] = (bf16_t)pv[1];
                hi.h[0] = (bf16_t)pv[2]; hi.h[1] = (bf16_t)pv[3];
                uu[blk][0] = lo.u; uu[blk][1] = hi.u;
            }
            int x0 = __builtin_amdgcn_ds_bpermute(addrA, (int)uu[0][0]);
            int y0 = __builtin_amdgcn_ds_bpermute(addrA, (int)uu[1][0]);
            int x1 = __builtin_amdgcn_ds_bpermute(addrA, (int)uu[0][1]);
            int y1 = __builtin_amdgcn_ds_bpermute(addrA, (int)uu[1][1]);
            int x2 = __builtin_amdgcn_ds_bpermute(addrB, (int)uu[0][0]);
            int y2 = __builtin_amdgcn_ds_bpermute(addrB, (int)uu[1][0]);
            int x3 = __builtin_amdgcn_ds_bpermute(addrB, (int)uu[0][1]);
            int y3 = __builtin_amdgcn_ds_bpermute(addrB, (int)uu[1][1]);
            I4B c;
            c.i = (i32x4){qlo ? x0 : y0, qlo ? x1 : y1, qlo ? x2 : y2, qlo ? x3 : y3};
            pa[g] = c.v;
        }

        __syncthreads();   // B1: drains V(lt) + K(next); all Ks[cb] reads done

        // ---- PV: U[q][d] += P[q][t] * V[d][t] over the 32-t tile
        const bf16_t* Vb = sm + 24576;
        __builtin_amdgcn_s_setprio(1);
        #pragma unroll
        for (int h = 0; h < 6; ++h) {
            #pragma unroll
            for (int n2 = 0; n2 < 4; ++n2) {
                bf16x8 bv = *(const bf16x8*)(Vb + (size_t)(h * 64 + n2 * 16 + l16) * 32 + vswz);
                U[h][n2] = MFMA16(pa[h], bv, U[h][n2]);
            }
        }
        __builtin_amdgcn_s_setprio(0);

        __syncthreads();   // B2: Vs reads done before next tile's V staging
    }

    // ---- epilogue: direct per-wave outputs
    #pragma unroll
    for (int g = 0; g < 6; ++g) {
        float l = lacc[g], l2 = l2acc[g];
        l  += __shfl_xor(l, 16, 64);  l  += __shfl_xor(l, 32, 64);
        l2 += __shfl_xor(l2, 16, 64); l2 += __shfl_xor(l2, 32, 64);
        if (quad == 0) {
            const size_t o = ((size_t)tq * 48 + b * 6 + g) * TT + qt * 64 + wid * 16 + l16;
            lp[o] = l; l2p[o] = l2;
        }
    }

    #pragma unroll
    for (int h = 0; h < 6; ++h) {
        float* Ub = Up + ((((size_t)tq * 8 + b) * 6 + h) * TT + qt * 64 + wid * 16) * 64;
        #pragma unroll
        for (int n2 = 0; n2 < 4; ++n2)
            #pragma unroll
            for (int r = 0; r < 4; ++r)
                Ub[(size_t)(quad * 4 + r) * 64 + n2 * 16 + l16] = U[h][n2][r];
    }
}

// ---------------------------------------------------------------------------
// K2b: stats, 48 blocks x 1024 thr (no atomics, no memsets):
//   linv[bg][q] = 1/sum_p lp[p][bg][q];  sq[bg] = sum_q l2/l^2
//   vr[b][g*64+d] = sum_tt vrp[tt][b][g*64+d]   (16 tile partials)
// ---------------------------------------------------------------------------
__global__ __launch_bounds__(1024) void stats_kernel(
    const float* __restrict__ lp, const float* __restrict__ l2p,
    const float* __restrict__ vrp,
    float* __restrict__ linv, float* __restrict__ sq, float* __restrict__ vr)
{
    const int bg = blockIdx.x, tid = threadIdx.x;
    const int b = bg / 6, g = bg - b * 6;

    __shared__ float red[16];
    __shared__ float vred[8][64];

    const int q = tid;
    const float l  = lp [(size_t)bg * TT + q] + lp [(size_t)(48 + bg) * TT + q]
                   + lp [(size_t)(96 + bg) * TT + q] + lp [(size_t)(144 + bg) * TT + q];
    const float l2 = l2p[(size_t)bg * TT + q] + l2p[(size_t)(48 + bg) * TT + q]
                   + l2p[(size_t)(96 + bg) * TT + q] + l2p[(size_t)(144 + bg) * TT + q];
    const float inv = 1.0f / l;
    linv[bg * TT + q] = inv;
    float c = l2 * inv * inv;
    #pragma unroll
    for (int off = 1; off < 64; off <<= 1) c += __shfl_xor(c, off, 64);
    if ((tid & 63) == 0) red[tid >> 6] = c;

    if (tid < 512) {
        const int d = tid & 63, ck = tid >> 6;   // 8 chunks x 2 tiles
        float s = 0.f;
        #pragma unroll
        for (int t2 = 0; t2 < 2; ++t2) {
            const int t = ck * 2 + t2;
            s += vrp[((size_t)t * 8 + b) * CC + g * 64 + d];
        }
        vred[ck][d] = s;
    }
    __syncthreads();
    if (tid == 0) {
        float s = 0.f;
        #pragma unroll
        for (int k = 0; k < 16; ++k) s += red[k];
        sq[bg] = s;
    }
    if (tid < 64) {
        float s = 0.f;
        #pragma unroll
        for (int k = 0; k < 8; ++k) s += vred[k][tid];
        vr[b * CC + g * 64 + tid] = s;
    }
}

// ---------------------------------------------------------------------------
// K3: projection + fused InstanceNorm affine + bias + transpose.
// bf16 projW, cached partial loads (L3), unroll-2 k-loop.
// Grid (64,8): 16-t tiles -> 512 blocks = 2 blocks/CU.
// ---------------------------------------------------------------------------
__global__ __launch_bounds__(256) void proj_kernel(
    const float* __restrict__ Up,
    const float* __restrict__ linv,
    const float* __restrict__ vrs,
    const float* __restrict__ sumsq,
    const float* __restrict__ gamma,
    const float* __restrict__ beta,
    const bf16_t* __restrict__ projW,
    const float* __restrict__ projb,
    float* __restrict__ out)
{
    const int ts = blockIdx.x;
    const int b  = blockIdx.y;
    const int t0 = ts * 16;
    const int tid = threadIdx.x, lane = tid & 63, wid = tid >> 6;
    const int quad = lane >> 4, l16 = lane & 15;

    __shared__ float Ac[6], Cc[6], pb[CC];
    if (tid < 6) {
        const float ss  = sumsq[b * NHH + tid];
        const float var = fmaxf(ss - 1.0f, 0.0f) * (1.0f / 1048576.0f);
        const float a   = gamma[tid] * rsqrtf(var + 1e-5f);
        Ac[tid] = a;
        Cc[tid] = beta[tid] - a * (1.0f / 1024.0f);
    }
    for (int i = tid; i < CC; i += 256) pb[i] = projb[i];
    __syncthreads();

    f32x4 acc[6];
    const f32x4 zero = {0.f, 0.f, 0.f, 0.f};
    #pragma unroll
    for (int mi = 0; mi < 6; ++mi) acc[mi] = zero;

    constexpr size_t PST = (size_t)BB * NHH * TT * 64;
    const float* Ub = Up + (size_t)b * (NHH * TT * 64);
    #pragma unroll 2
    for (int k0 = 0; k0 < CC; k0 += 32) {
        const int tl = t0 + l16;
        const int baseoff = tl * CC + k0 + quad * 8;
        const int hh = baseoff >> 16;                 // constant over j (8-aligned)
        const int d0 = baseoff & 63;                  // d of j=0; d0+7 <= 63
        const float li = linv[b * 6144 + (baseoff >> 6)];
        const float Al = Ac[hh] * li;
        const float Cb = Cc[hh];
        f32x4 u0 = *(const f32x4*)(Ub + baseoff)
                 + *(const f32x4*)(Ub + PST + baseoff)
                 + *(const f32x4*)(Ub + 2 * PST + baseoff)
                 + *(const f32x4*)(Ub + 3 * PST + baseoff);
        f32x4 u1 = *(const f32x4*)(Ub + baseoff + 4)
                 + *(const f32x4*)(Ub + PST + baseoff + 4)
                 + *(const f32x4*)(Ub + 2 * PST + baseoff + 4)
                 + *(const f32x4*)(Ub + 3 * PST + baseoff + 4);
        U8 z;
        #pragma unroll
        for (int j = 0; j < 8; ++j) {
            const float uv = (j < 4) ? u0[j] : u1[j - 4];
            z.h[j] = (bf16_t)(Al * uv + Cb * vrs[b * CC + hh * 64 + d0 + j]);
        }
        bf16x8 bfr = *(const bf16x8*)&z;
        #pragma unroll
        for (int mi = 0; mi < 6; ++mi) {
            const int o = wid * 96 + mi * 16 + l16;
            bf16x8 afr = *(const bf16x8*)(projW + (size_t)o * CC + k0 + quad * 8);
            acc[mi] = MFMA16(afr, bfr, acc[mi]);
        }
    }

    #pragma unroll
    for (int mi = 0; mi < 6; ++mi)
        #pragma unroll
        for (int r = 0; r < 4; ++r) {
            const int o  = wid * 96 + mi * 16 + quad * 4 + r;
            const int tl = t0 + l16;
            out[((size_t)b * CC + o) * TT + tl] = acc[mi][r] + pb[o];
        }
}

// ---------------------------------------------------------------------------
extern "C" void kernel_launch(void* const* d_in, const int* in_sizes, int n_in,
                              void* d_out, int out_size, void* d_ws, size_t ws_size,
                              hipStream_t stream)
{
    float* outp = (float*)d_out;
    char* ws = (char*)d_ws;

    size_t off = 0;
    auto alloc = [&](size_t bytes) {
        void* p = ws + off;
        off += (bytes + 255) & ~(size_t)255;
        return p;
    };

    const size_t szT = (size_t)BB * TT * CC * sizeof(bf16_t);   // 6.29 MB
    const size_t szW = (size_t)CC * CC * sizeof(bf16_t);        // 288 KB

    bf16_t* qTb = (bf16_t*)alloc(szT);
    bf16_t* kTb = (bf16_t*)alloc(szT);
    bf16_t* vmb = (bf16_t*)alloc(szT);
    bf16_t* Wqb = (bf16_t*)alloc(szW);
    bf16_t* Wkb = (bf16_t*)alloc(szW);
    bf16_t* Wvb = (bf16_t*)alloc(szW);
    bf16_t* PWb = (bf16_t*)alloc(szW);
    float*  Uh  = (float*)alloc((size_t)4 * BB * NHH * TT * 64 * sizeof(float)); // 50.3 MB
    float*  lpb = (float*)alloc((size_t)4 * 48 * TT * sizeof(float));
    float*  l2b = (float*)alloc((size_t)4 * 48 * TT * sizeof(float));
    float*  lv  = (float*)alloc((size_t)48 * TT * sizeof(float));
    float*  vrp = (float*)alloc((size_t)16 * BB * CC * sizeof(float));
    float*  vr  = (float*)alloc((size_t)BB * CC * sizeof(float));
    float*  sq  = (float*)alloc(48 * sizeof(float));

    castw_kernel<<<dim3(72, 4), 256, 0, stream>>>(
        (const float*)d_in[1], (const float*)d_in[2], (const float*)d_in[3],
        (const float*)d_in[7], Wqb, Wkb, Wvb, PWb);
    qkv_kernel<<<dim3(16, 6, 8), 256, 0, stream>>>(
        (const float*)d_in[0], Wqb, Wkb, Wvb, qTb, kTb, vmb, vrp);
    fused_attn<<<512, 256, 0, stream>>>(
        qTb, kTb, vmb, (const float*)d_in[4], Uh, lpb, l2b);
    stats_kernel<<<48, 1024, 0, stream>>>(lpb, l2b, vrp, lv, sq, vr);
    proj_kernel<<<dim3(64, 8), 256, 0, stream>>>(
        Uh, lv, vr, sq, (const float*)d_in[5], (const float*)d_in[6],
        PWb, (const float*)d_in[8], outp);
}